// Round 1
// 204.144 us; speedup vs baseline: 1.0236x; 1.0236x over previous
//
#include <hip/hip_runtime.h>

// MultiHeadAttention: N=4, S=T=2048, E=512, H=8, HD=64. fp32 in/out, bf16 MFMA compute.
// R3: register-resident P (k-relabeled PV, no P^T LDS round-trip, 2 barriers/step),
// native cvt_pk bf16 packing, scale folded into Q projection, defer-rescale,
// LDS 40960B -> 4 blocks/CU, setprio around MFMA clusters, gemm_out retiled 64x128.

#define DEV __device__ __forceinline__

typedef unsigned short u16;
typedef unsigned int u32;
typedef __bf16 bf16x8 __attribute__((ext_vector_type(8)));
typedef float f32x4 __attribute__((ext_vector_type(4)));
typedef u32 u32x4 __attribute__((ext_vector_type(4)));

#define MFMA_BF16(A, B, C) __builtin_amdgcn_mfma_f32_16x16x32_bf16(A, B, C, 0, 0, 0)

DEV u16 f2bf(float f) {  // RNE
  u32 u = __builtin_bit_cast(u32, f);
  u += 0x7fffu + ((u >> 16) & 1u);
  return (u16)(u >> 16);
}

// async global->LDS, 16B per lane. LDS dst must be lane-contiguous (wave-uniform base + lane*16).
DEV void cp16(void* l, const void* g) {
  __builtin_amdgcn_global_load_lds(
      (const __attribute__((address_space(1))) u32*)g,
      (__attribute__((address_space(3))) u32*)l, 16, 0, 0);
}

// ---------------- casts ----------------
__global__ __launch_bounds__(256) void cast3(const float* __restrict__ q,
                                             const float* __restrict__ k,
                                             const float* __restrict__ v,
                                             u16* qo, u16* ko, u16* vo) {
  const float* s = (blockIdx.y == 0) ? q : (blockIdx.y == 1) ? k : v;
  u16* d = (blockIdx.y == 0) ? qo : (blockIdx.y == 1) ? ko : vo;
  int i = blockIdx.x * 256 + threadIdx.x;  // grid.x*256 == elem4 count exactly
  float4 f = ((const float4*)s)[i];
  ushort4 o;
  o.x = f2bf(f.x); o.y = f2bf(f.y); o.z = f2bf(f.z); o.w = f2bf(f.w);
  ((ushort4*)d)[i] = o;
}

__global__ __launch_bounds__(256) void cast4(const float* __restrict__ a,
                                             const float* __restrict__ b,
                                             const float* __restrict__ c,
                                             const float* __restrict__ d2,
                                             u16* ao, u16* bo, u16* co, u16* do_) {
  int y = blockIdx.y;
  const float* s = (y == 0) ? a : (y == 1) ? b : (y == 2) ? c : d2;
  u16* d = (y == 0) ? ao : (y == 1) ? bo : (y == 2) ? co : do_;
  int i = blockIdx.x * 256 + threadIdx.x;
  float4 f = ((const float4*)s)[i];
  ushort4 o;
  o.x = f2bf(f.x); o.y = f2bf(f.y); o.z = f2bf(f.z); o.w = f2bf(f.w);
  ((ushort4*)d)[i] = o;
}

// ---------------- GEMM core: C[m,n] = sum_k A[m,k]*W[n,k] ----------------
// 128x128 tile, BK=32, 4 waves (2x2 of 64x64), global_load_lds width-16 staging.
DEV void gemm_loop(const u16* __restrict__ A, const u16* __restrict__ W,
                   u16* As, u16* Bs, int m0, int n0, int tid, f32x4 acc[4][4]) {
  const int lane = tid & 63, wid = tid >> 6;
  const int wm = wid & 1, wn = wid >> 1;
  const int l15 = lane & 15, l4 = lane >> 4;
  for (int kt = 0; kt < 512; kt += 32) {
    __syncthreads();
#pragma unroll
    for (int i = 0; i < 2; ++i) {
      int c = tid + 256 * i;
      int row = c >> 2, kc = (c & 3) * 8;
      cp16(&As[c * 8], A + (m0 + row) * 512 + kt + kc);
      cp16(&Bs[c * 8], W + (n0 + row) * 512 + kt + kc);
    }
    __syncthreads();
    bf16x8 af[4], bfr[4];
#pragma unroll
    for (int f = 0; f < 4; ++f) {
      af[f]  = *(const bf16x8*)&As[(wm * 64 + f * 16 + l15) * 32 + l4 * 8];
      bfr[f] = *(const bf16x8*)&Bs[(wn * 64 + f * 16 + l15) * 32 + l4 * 8];
    }
#pragma unroll
    for (int fm = 0; fm < 4; ++fm)
#pragma unroll
      for (int fn = 0; fn < 4; ++fn)
        acc[fm][fn] = MFMA_BF16(af[fm], bfr[fn], acc[fm][fn]);
  }
}

// Fused QKV projection: grid (12, 64); blockIdx.x>>2 selects Q/K/V problem.
// Q output is pre-scaled by (1/sqrt(HD))*log2(e) so attn scores land in exp2 domain.
__global__ __launch_bounds__(256) void gemm_qkv(
    const u16* __restrict__ qx, const u16* __restrict__ kx, const u16* __restrict__ vx,
    const u16* __restrict__ wq, const u16* __restrict__ wk, const u16* __restrict__ wv,
    const float* __restrict__ bq, const float* __restrict__ bk, const float* __restrict__ bv,
    u16* qp, u16* kp, u16* vp) {
  __shared__ u16 As[128 * 32];
  __shared__ u16 Bs[128 * 32];
  const int wsel = blockIdx.x >> 2;
  const u16* A = (wsel == 0) ? qx : (wsel == 1) ? kx : vx;
  const u16* W = (wsel == 0) ? wq : (wsel == 1) ? wk : wv;
  const float* bias = (wsel == 0) ? bq : (wsel == 1) ? bk : bv;
  u16* C = (wsel == 0) ? qp : (wsel == 1) ? kp : vp;
  const int n0 = (blockIdx.x & 3) * 128, m0 = blockIdx.y * 128;
  const int tid = threadIdx.x, lane = tid & 63, wid = tid >> 6;
  const int wm = wid & 1, wn = wid >> 1;
  const int l15 = lane & 15, l4 = lane >> 4;
  const float osc = (wsel == 0) ? 0.18033688f : 1.0f;  // (1/8)*log2(e) folded into Q

  f32x4 acc[4][4] = {};
  gemm_loop(A, W, As, Bs, m0, n0, tid, acc);

#pragma unroll
  for (int fn = 0; fn < 4; ++fn) {
    int col = n0 + wn * 64 + fn * 16 + l15;
    float bvv = bias[col];
#pragma unroll
    for (int fm = 0; fm < 4; ++fm) {
      int rowb = m0 + wm * 64 + fm * 16 + l4 * 4;
#pragma unroll
      for (int r = 0; r < 4; ++r)
        C[(rowb + r) * 512 + col] = f2bf((acc[fm][fn][r] + bvv) * osc);
    }
  }
}

// Final projection: fp32 out. 64x128 tile -> grid (4,128)=512 blocks (2/CU; the old
// 256-block config was exactly 1 block/CU and every barrier drain was exposed).
__global__ __launch_bounds__(256) void gemm_out(const u16* __restrict__ A,
                                                const u16* __restrict__ W,
                                                const float* __restrict__ bias,
                                                float* __restrict__ C) {
  __shared__ u16 As[64 * 32];
  __shared__ u16 Bs[128 * 32];
  const int n0 = blockIdx.x * 128, m0 = blockIdx.y * 64;
  const int tid = threadIdx.x, lane = tid & 63, wid = tid >> 6;
  const int wm = wid & 1, wn = wid >> 1;  // wave tile 32x64
  const int l15 = lane & 15, l4 = lane >> 4;

  f32x4 acc[2][4] = {};
  for (int kt = 0; kt < 512; kt += 32) {
    __syncthreads();
    {
      int row = tid >> 2, kc = (tid & 3) * 8;  // As: 256 chunks, one per thread
      cp16(&As[tid * 8], A + (m0 + row) * 512 + kt + kc);
    }
#pragma unroll
    for (int i = 0; i < 2; ++i) {  // Bs: 512 chunks
      int c = tid + 256 * i;
      int row = c >> 2, kc = (c & 3) * 8;
      cp16(&Bs[c * 8], W + (n0 + row) * 512 + kt + kc);
    }
    __syncthreads();
    bf16x8 af[2], bfr[4];
#pragma unroll
    for (int f = 0; f < 2; ++f)
      af[f] = *(const bf16x8*)&As[(wm * 32 + f * 16 + l15) * 32 + l4 * 8];
#pragma unroll
    for (int f = 0; f < 4; ++f)
      bfr[f] = *(const bf16x8*)&Bs[(wn * 64 + f * 16 + l15) * 32 + l4 * 8];
#pragma unroll
    for (int fm = 0; fm < 2; ++fm)
#pragma unroll
      for (int fn = 0; fn < 4; ++fn)
        acc[fm][fn] = MFMA_BF16(af[fm], bfr[fn], acc[fm][fn]);
  }

#pragma unroll
  for (int fn = 0; fn < 4; ++fn) {
    int col = n0 + wn * 64 + fn * 16 + l15;
    float bvv = bias[col];
#pragma unroll
    for (int fm = 0; fm < 2; ++fm) {
      int rowb = m0 + wm * 32 + fm * 16 + l4 * 4;
#pragma unroll
      for (int r = 0; r < 4; ++r)
        C[(rowb + r) * 512 + col] = acc[fm][fn][r] + bvv;
    }
  }
}

// ---------------- V transpose: vp[n][t][h*64+d] -> vt[nh*64+d][t] ----------------
__global__ __launch_bounds__(256) void transpose_v(const u16* __restrict__ vp,
                                                   u16* __restrict__ vt) {
  __shared__ u16 L[64 * 72];  // 64x64 tile, stride 72 breaks bank alignment
  const int bid = blockIdx.x;  // 1024 = 32 t-tiles x 32 nh
  const int nh = bid & 31, tt = bid >> 5;
  const int n = nh >> 3, h = nh & 7;
  const u16* src = vp + (n * 2048 + tt * 64) * 512 + h * 64;
  const int tid = threadIdx.x;
#pragma unroll
  for (int i = 0; i < 2; ++i) {
    int c = tid + 256 * i;
    int row = c >> 3, dg = c & 7;
    uint4 x = *(const uint4*)(src + row * 512 + dg * 8);
    *(uint4*)&L[row * 72 + dg * 8] = x;  // (row*72+dg*8)*2 is 16B-aligned (144=9*16)
  }
  __syncthreads();
  u16* dst = vt + nh * 64 * 2048 + tt * 64;
#pragma unroll
  for (int i = 0; i < 2; ++i) {
    int c = tid + 256 * i;
    int d = c >> 3, tg = c & 7;
    u16 e[8];
#pragma unroll
    for (int j = 0; j < 8; ++j) e[j] = L[(tg * 8 + j) * 72 + d];
    uint4 o;
    o.x = (u32)e[0] | ((u32)e[1] << 16);
    o.y = (u32)e[2] | ((u32)e[3] << 16);
    o.z = (u32)e[4] | ((u32)e[5] << 16);
    o.w = (u32)e[6] | ((u32)e[7] << 16);
    *(uint4*)(dst + d * 2048 + tg * 8) = o;
  }
}

// ---------------- Flash attention, causal, S^T formulation ----------------
// grid 1024 = 32 q-tiles (64 rows) x 32 nh; heavy q-tiles dispatched first.
// Per tile-step: S^T = K*Q^T (C/D rows = t), softmax over t per column m=l15,
// P kept in REGISTERS and fed to PV via k-relabeling: for mfma ks, k-slot j of
// lane l4=g means t = ks*32 + 16*(j>>2) + g*4 + (j&3) on BOTH operands (bijective
// onto [ks*32, ks*32+32) so the dot product is exact). V^T B-frags are read as
// two ds_read_b64 from the same swizzled LDS tile. No P^T LDS buffer, 2 barriers.
__global__ __launch_bounds__(256) void attn_kernel(const u16* __restrict__ Qg,
                                                   const u16* __restrict__ Kg,
                                                   const u16* __restrict__ Vt,
                                                   u16* __restrict__ Yg) {
  __shared__ u16 Qs[64 * 64];    // Q tile [m][d], source-swizzled chunks   (8 KB)
  __shared__ u16 Ks[128 * 64];   // K tile [t][d], source-swizzled chunks   (16 KB)
  __shared__ u16 Vts[64 * 128];  // V^T tile [d][t], source-swizzled chunks (16 KB)
  // total 40960 B -> exactly 4 blocks/CU

  const int bid = blockIdx.x;
  const int nh = bid & 31;
  const int qt = 31 - (bid >> 5);  // heavy (long) q-tiles first
  const int n = nh >> 3, h = nh & 7;
  const int tid = threadIdx.x, lane = tid & 63, w = tid >> 6;
  const int l15 = lane & 15, l4 = lane >> 4;
  const int s0 = qt * 64;

  const u16* Qb = Qg + (n * 2048 + s0) * 512 + h * 64;
  const u16* Kb = Kg + n * 2048 * 512 + h * 64;
  const u16* Vb = Vt + nh * 64 * 2048;

  // stage Q tile once
#pragma unroll
  for (int i = 0; i < 2; ++i) {
    int c = tid + 256 * i;
    int row = c >> 3, dg = (c & 7) ^ (row & 7);
    cp16(&Qs[c * 8], Qb + row * 512 + dg * 8);
  }
  __syncthreads();
  const int qr = w * 16 + l15;
  bf16x8 qf0 = *(const bf16x8*)&Qs[qr * 64 + ((l4 ^ (qr & 7)) * 8)];
  bf16x8 qf1 = *(const bf16x8*)&Qs[qr * 64 + (((4 + l4) ^ (qr & 7)) * 8)];

  f32x4 accO[4] = {};
  float mrow = -1e30f, lrow = 0.f;      // softmax state for column m = l15 (s = s0+w*16+l15)
  const int sgl = s0 + w * 16 + l15;

  const int ntiles = (qt >> 1) + 1;
  for (int it = 0; it < ntiles; ++it) {
    const int t0 = it * 128;
    __syncthreads();  // prior QK^T/PV reads of Ks/Vts complete
#pragma unroll
    for (int i = 0; i < 4; ++i) {  // K tile: 1024 chunks
      int c = tid + 256 * i;
      int t = c >> 3, dg = (c & 7) ^ (t & 7);
      cp16(&Ks[c * 8], Kb + (t0 + t) * 512 + dg * 8);
    }
#pragma unroll
    for (int i = 0; i < 4; ++i) {  // V^T tile: 1024 chunks (pre-transposed global)
      int c = tid + 256 * i;
      int d = c >> 4, tgs = c & 15;
      cp16(&Vts[c * 8], Vb + d * 2048 + t0 + ((tgs ^ (d & 15)) * 8));
    }
    __syncthreads();

    // ---- S^T = K Q^T : 8 frags along t (rows), cols m = l15. Q pre-scaled. ----
    f32x4 st[8];
    __builtin_amdgcn_s_setprio(1);
#pragma unroll
    for (int fn = 0; fn < 8; ++fn) {
      int tr = fn * 16 + l15;
      bf16x8 k0 = *(const bf16x8*)&Ks[tr * 64 + ((l4 ^ (tr & 7)) * 8)];
      bf16x8 k1 = *(const bf16x8*)&Ks[tr * 64 + (((4 + l4) ^ (tr & 7)) * 8)];
      f32x4 a = {};
      a = MFMA_BF16(k0, qf0, a);
      st[fn] = MFMA_BF16(k1, qf1, a);
    }
    __builtin_amdgcn_s_setprio(0);

    // ---- online softmax, exp2 domain; this lane owns column m = l15 ----
    const bool diag = (t0 + 128 > s0);  // true only on the last tile
    float rmax = -1e30f;
#pragma unroll
    for (int fn = 0; fn < 8; ++fn)
#pragma unroll
      for (int r = 0; r < 4; ++r) {
        float v = st[fn][r];
        if (diag) {
          int tg = t0 + fn * 16 + l4 * 4 + r;
          if (tg > sgl) v = -1e30f;
        }
        st[fn][r] = v;
        rmax = fmaxf(rmax, v);
      }
    rmax = fmaxf(rmax, __shfl_xor(rmax, 16));
    rmax = fmaxf(rmax, __shfl_xor(rmax, 32));
    // defer-rescale: only pay the alpha shuffle + O rescale when the running max
    // grew by >10 (exp2 units); P then bounded by 2^10, exactness preserved.
    if (__any(rmax > mrow + 10.f)) {
      float mnew = fmaxf(mrow, rmax);
      float alpha = __builtin_amdgcn_exp2f(mrow - mnew);
      mrow = mnew;
      lrow *= alpha;
      float aO[4];
#pragma unroll
      for (int r = 0; r < 4; ++r) aO[r] = __shfl(alpha, (lane & 48) | (l4 * 4 + r));
#pragma unroll
      for (int fd = 0; fd < 4; ++fd)
#pragma unroll
        for (int r = 0; r < 4; ++r) accO[fd][r] *= aO[r];
    }
    float rsum = 0.f;
#pragma unroll
    for (int fn = 0; fn < 8; ++fn)
#pragma unroll
      for (int r = 0; r < 4; ++r) {
        float p = __builtin_amdgcn_exp2f(st[fn][r] - mrow);
        st[fn][r] = p;
        rsum += p;
      }
    rsum += __shfl_xor(rsum, 16);
    rsum += __shfl_xor(rsum, 32);
    lrow += rsum;

    // ---- P -> bf16 A-frags in registers (compiler emits v_cvt_pk_bf16_f32) ----
    // pa[ks] slot j = P[m][ks*32 + 16*(j>>2) + l4*4 + (j&3)]
    bf16x8 pa[4];
#pragma unroll
    for (int ks = 0; ks < 4; ++ks) {
      bf16x8 t;
      t[0] = (__bf16)st[2 * ks][0];     t[1] = (__bf16)st[2 * ks][1];
      t[2] = (__bf16)st[2 * ks][2];     t[3] = (__bf16)st[2 * ks][3];
      t[4] = (__bf16)st[2 * ks + 1][0]; t[5] = (__bf16)st[2 * ks + 1][1];
      t[6] = (__bf16)st[2 * ks + 1][2]; t[7] = (__bf16)st[2 * ks + 1][3];
      pa[ks] = t;
    }

    // ---- O += P V : B-frag slot j = V[ks*32 + 16*(j>>2) + l4*4 + (j&3)][d] ----
    __builtin_amdgcn_s_setprio(1);
#pragma unroll
    for (int ks = 0; ks < 4; ++ks) {
#pragma unroll
      for (int fd = 0; fd < 4; ++fd) {
        int d = fd * 16 + l15;
        const u16* vrow = &Vts[d * 128];
        // global 4-t group tg4 = ks*8 + 4h + l4 lives at LDS chunk (tg4>>1)^(d&15), half tg4&1
        uint2 v0 = *(const uint2*)&vrow[(((ks * 4 + (l4 >> 1)) ^ l15) * 8) + (l4 & 1) * 4];
        uint2 v1 = *(const uint2*)&vrow[(((ks * 4 + 2 + (l4 >> 1)) ^ l15) * 8) + (l4 & 1) * 4];
        u32x4 bw; bw.x = v0.x; bw.y = v0.y; bw.z = v1.x; bw.w = v1.y;
        accO[fd] = MFMA_BF16(pa[ks], __builtin_bit_cast(bf16x8, bw), accO[fd]);
      }
    }
    __builtin_amdgcn_s_setprio(0);
  }

  // ---- epilogue ----
  float lO[4];
#pragma unroll
  for (int r = 0; r < 4; ++r) lO[r] = __shfl(lrow, (lane & 48) | (l4 * 4 + r));
#pragma unroll
  for (int fd = 0; fd < 4; ++fd)
#pragma unroll
    for (int r = 0; r < 4; ++r) {
      int row = s0 + w * 16 + l4 * 4 + r;
      int col = h * 64 + fd * 16 + l15;
      Yg[(n * 2048 + row) * 512 + col] = f2bf(accO[fd][r] / lO[r]);
    }
}

extern "C" void kernel_launch(void* const* d_in, const int* in_sizes, int n_in,
                              void* d_out, int out_size, void* d_ws, size_t ws_size,
                              hipStream_t stream) {
  (void)in_sizes; (void)n_in; (void)out_size; (void)ws_size;
  const float* query = (const float*)d_in[0];
  const float* key_  = (const float*)d_in[1];
  const float* value = (const float*)d_in[2];
  // d_in[3] = attn_mask (tril) — causal, applied structurally
  const float* Wq = (const float*)d_in[4];
  const float* bq = (const float*)d_in[5];
  const float* Wk = (const float*)d_in[6];
  const float* bk = (const float*)d_in[7];
  const float* Wv = (const float*)d_in[8];
  const float* bv = (const float*)d_in[9];
  const float* Wp = (const float*)d_in[10];
  const float* bp = (const float*)d_in[11];

  char* ws = (char*)d_ws;  // 50 MB total
  u16* qx  = (u16*)(ws);                // 8 MB; reused as y after q-proj
  u16* kx  = (u16*)(ws + 8388608);      // 8 MB; reused as vt after k-proj
  u16* vx  = (u16*)(ws + 16777216);     // 8 MB
  u16* wqx = (u16*)(ws + 25165824);
  u16* wkx = (u16*)(ws + 25690112);
  u16* wvx = (u16*)(ws + 26214400);
  u16* wpx = (u16*)(ws + 26738688);
  u16* qp  = (u16*)(ws + 27262976);     // 8 MB
  u16* kp  = (u16*)(ws + 35651584);     // 8 MB
  u16* vp  = (u16*)(ws + 44040192);     // 8 MB
  u16* y   = qx;
  u16* vt  = kx;  // kx dead after gemm_qkv

  cast3<<<dim3(4096, 3), 256, 0, stream>>>(query, key_, value, qx, kx, vx);
  cast4<<<dim3(256, 4), 256, 0, stream>>>(Wq, Wk, Wv, Wp, wqx, wkx, wvx, wpx);

  gemm_qkv<<<dim3(12, 64), 256, 0, stream>>>(qx, kx, vx, wqx, wkx, wvx,
                                             bq, bk, bv, qp, kp, vp);
  transpose_v<<<1024, 256, 0, stream>>>(vp, vt);
  attn_kernel<<<1024, 256, 0, stream>>>(qp, kp, vt, y);
  gemm_out<<<dim3(4, 128), 256, 0, stream>>>(y, wpx, bp, (float*)d_out);
}

// Round 2
// 195.216 us; speedup vs baseline: 1.0704x; 1.0457x over previous
//
#include <hip/hip_runtime.h>

// MultiHeadAttention: N=4, S=T=2048, E=512, H=8, HD=64. fp32 in/out, bf16 MFMA compute.
// R4: counted-vmcnt staggered pipeline in attn (no vmcnt(0) drains in steady state,
// raw s_barrier, K/V prefetch hidden under compute, same 40KB LDS -> 4 blocks/CU),
// b128 PV reads via permuted V^T global layout, double-buffered GEMM loops with
// single-barrier counted waits, casts merged into one dispatch (5 total).

#define DEV __device__ __forceinline__

typedef unsigned short u16;
typedef unsigned int u32;
typedef __bf16 bf16x8 __attribute__((ext_vector_type(8)));
typedef float f32x4 __attribute__((ext_vector_type(4)));

#define MFMA_BF16(A, B, C) __builtin_amdgcn_mfma_f32_16x16x32_bf16(A, B, C, 0, 0, 0)

DEV u16 f2bf(float f) {  // RNE
  u32 u = __builtin_bit_cast(u32, f);
  u += 0x7fffu + ((u >> 16) & 1u);
  return (u16)(u >> 16);
}

// async global->LDS, 16B per lane. LDS dst must be lane-contiguous (wave-uniform base + lane*16).
DEV void cp16(void* l, const void* g) {
  __builtin_amdgcn_global_load_lds(
      (const __attribute__((address_space(1))) u32*)g,
      (__attribute__((address_space(3))) u32*)l, 16, 0, 0);
}

#define WAIT_VM(N) asm volatile("s_waitcnt vmcnt(" #N ")" ::: "memory")
#define WAIT_VMLG  asm volatile("s_waitcnt vmcnt(0) lgkmcnt(0)" ::: "memory")
#define WAIT_LG    asm volatile("s_waitcnt lgkmcnt(0)" ::: "memory")
#define BARRIER    asm volatile("s_barrier" ::: "memory")

// ---------------- merged casts: q/k/v (4096 blocks each) + 4 weights (256 each) ----
__global__ __launch_bounds__(256) void cast_all(
    const float* __restrict__ q, const float* __restrict__ k, const float* __restrict__ v,
    const float* __restrict__ wq, const float* __restrict__ wk,
    const float* __restrict__ wv, const float* __restrict__ wp,
    u16* qo, u16* ko, u16* vo, u16* wqo, u16* wko, u16* wvo, u16* wpo) {
  int b = blockIdx.x;
  const float* s;
  u16* d;
  int i;
  if (b < 12288) {
    int t = b >> 12;
    s = (t == 0) ? q : (t == 1) ? k : v;
    d = (t == 0) ? qo : (t == 1) ? ko : vo;
    i = (b & 4095) * 256 + threadIdx.x;
  } else {
    int t = (b - 12288) >> 8;
    s = (t == 0) ? wq : (t == 1) ? wk : (t == 2) ? wv : wp;
    d = (t == 0) ? wqo : (t == 1) ? wko : (t == 2) ? wvo : wpo;
    i = ((b - 12288) & 255) * 256 + threadIdx.x;
  }
  float4 f = ((const float4*)s)[i];
  ushort4 o;
  o.x = f2bf(f.x); o.y = f2bf(f.y); o.z = f2bf(f.z); o.w = f2bf(f.w);
  ((ushort4*)d)[i] = o;
}

// ---------------- GEMM core: C[m,n] = sum_k A[m,k]*W[n,k] ----------------
// 128x128 tile, BK=32, 4 waves, double-buffered LDS, counted-wait single barrier/iter:
// stage(next) issued right after the barrier; at next iter's top the drain is cheap
// because the loads had a full MFMA phase to land.
DEV void gemm_stage(const u16* __restrict__ A, const u16* __restrict__ W,
                    u16* As, u16* Bs, int m0, int n0, int kt, int tid) {
#pragma unroll
  for (int i = 0; i < 2; ++i) {
    int c = tid + 256 * i;
    int row = c >> 2, kc = (c & 3) * 8;
    cp16(&As[c * 8], A + (m0 + row) * 512 + kt + kc);
    cp16(&Bs[c * 8], W + (n0 + row) * 512 + kt + kc);
  }
}

DEV void gemm_loop(const u16* __restrict__ A, const u16* __restrict__ W,
                   u16* As, u16* Bs,  // each sized 2*128*32
                   int m0, int n0, int tid, f32x4 acc[4][4]) {
  const int lane = tid & 63, wid = tid >> 6;
  const int wm = wid & 1, wn = wid >> 1;
  const int l15 = lane & 15, l4 = lane >> 4;
  gemm_stage(A, W, As, Bs, m0, n0, 0, tid);
  for (int it = 0; it < 16; ++it) {
    WAIT_VMLG;   // cur buffer staged (4 loads from prev iter) + my prev ds_reads done
    BARRIER;     // all waves drained -> cur fully written, prev reads complete
    const u16* Ac = As + (it & 1) * 4096;
    const u16* Bc = Bs + (it & 1) * 4096;
    if (it < 15)
      gemm_stage(A, W, As + ((it + 1) & 1) * 4096, Bs + ((it + 1) & 1) * 4096,
                 m0, n0, (it + 1) * 32, tid);
    bf16x8 af[4], bfr[4];
#pragma unroll
    for (int f = 0; f < 4; ++f) {
      af[f]  = *(const bf16x8*)&Ac[(wm * 64 + f * 16 + l15) * 32 + l4 * 8];
      bfr[f] = *(const bf16x8*)&Bc[(wn * 64 + f * 16 + l15) * 32 + l4 * 8];
    }
    __builtin_amdgcn_s_setprio(1);
#pragma unroll
    for (int fm = 0; fm < 4; ++fm)
#pragma unroll
      for (int fn = 0; fn < 4; ++fn)
        acc[fm][fn] = MFMA_BF16(af[fm], bfr[fn], acc[fm][fn]);
    __builtin_amdgcn_s_setprio(0);
  }
}

// Fused QKV projection: grid (12, 64); blockIdx.x>>2 selects Q/K/V problem.
// Q output is pre-scaled by (1/sqrt(HD))*log2(e) so attn scores land in exp2 domain.
__global__ __launch_bounds__(256) void gemm_qkv(
    const u16* __restrict__ qx, const u16* __restrict__ kx, const u16* __restrict__ vx,
    const u16* __restrict__ wq, const u16* __restrict__ wk, const u16* __restrict__ wv,
    const float* __restrict__ bq, const float* __restrict__ bk, const float* __restrict__ bv,
    u16* qp, u16* kp, u16* vp) {
  __shared__ u16 As[2 * 128 * 32];
  __shared__ u16 Bs[2 * 128 * 32];
  const int wsel = blockIdx.x >> 2;
  const u16* A = (wsel == 0) ? qx : (wsel == 1) ? kx : vx;
  const u16* W = (wsel == 0) ? wq : (wsel == 1) ? wk : wv;
  const float* bias = (wsel == 0) ? bq : (wsel == 1) ? bk : bv;
  u16* C = (wsel == 0) ? qp : (wsel == 1) ? kp : vp;
  const int n0 = (blockIdx.x & 3) * 128, m0 = blockIdx.y * 128;
  const int tid = threadIdx.x, lane = tid & 63, wid = tid >> 6;
  const int wm = wid & 1, wn = wid >> 1;
  const int l15 = lane & 15, l4 = lane >> 4;
  const float osc = (wsel == 0) ? 0.18033688f : 1.0f;  // (1/8)*log2(e) folded into Q

  f32x4 acc[4][4] = {};
  gemm_loop(A, W, As, Bs, m0, n0, tid, acc);

#pragma unroll
  for (int fn = 0; fn < 4; ++fn) {
    int col = n0 + wn * 64 + fn * 16 + l15;
    float bvv = bias[col];
#pragma unroll
    for (int fm = 0; fm < 4; ++fm) {
      int rowb = m0 + wm * 64 + fm * 16 + l4 * 4;
#pragma unroll
      for (int r = 0; r < 4; ++r)
        C[(rowb + r) * 512 + col] = f2bf((acc[fm][fn][r] + bvv) * osc);
    }
  }
}

// Final projection: fp32 out, 64x128 tile, grid (4,128)=512 blocks, double-buffered.
__global__ __launch_bounds__(256) void gemm_out(const u16* __restrict__ A,
                                                const u16* __restrict__ W,
                                                const float* __restrict__ bias,
                                                float* __restrict__ C) {
  __shared__ u16 As[2 * 64 * 32];
  __shared__ u16 Bs[2 * 128 * 32];
  const int n0 = blockIdx.x * 128, m0 = blockIdx.y * 64;
  const int tid = threadIdx.x, lane = tid & 63, wid = tid >> 6;
  const int wm = wid & 1, wn = wid >> 1;  // wave tile 32x64
  const int l15 = lane & 15, l4 = lane >> 4;

  auto stage = [&](u16* Asb, u16* Bsb, int kt) {
    {
      int row = tid >> 2, kc = (tid & 3) * 8;
      cp16(&Asb[tid * 8], A + (m0 + row) * 512 + kt + kc);
    }
#pragma unroll
    for (int i = 0; i < 2; ++i) {
      int c = tid + 256 * i;
      int row = c >> 2, kc = (c & 3) * 8;
      cp16(&Bsb[c * 8], W + (n0 + row) * 512 + kt + kc);
    }
  };

  f32x4 acc[2][4] = {};
  stage(As, Bs, 0);
  for (int it = 0; it < 16; ++it) {
    WAIT_VMLG;
    BARRIER;
    const u16* Ac = As + (it & 1) * 2048;
    const u16* Bc = Bs + (it & 1) * 4096;
    if (it < 15)
      stage(As + ((it + 1) & 1) * 2048, Bs + ((it + 1) & 1) * 4096, (it + 1) * 32);
    bf16x8 af[2], bfr[4];
#pragma unroll
    for (int f = 0; f < 2; ++f)
      af[f] = *(const bf16x8*)&Ac[(wm * 32 + f * 16 + l15) * 32 + l4 * 8];
#pragma unroll
    for (int f = 0; f < 4; ++f)
      bfr[f] = *(const bf16x8*)&Bc[(wn * 64 + f * 16 + l15) * 32 + l4 * 8];
    __builtin_amdgcn_s_setprio(1);
#pragma unroll
    for (int fm = 0; fm < 2; ++fm)
#pragma unroll
      for (int fn = 0; fn < 4; ++fn)
        acc[fm][fn] = MFMA_BF16(af[fm], bfr[fn], acc[fm][fn]);
    __builtin_amdgcn_s_setprio(0);
  }

#pragma unroll
  for (int fn = 0; fn < 4; ++fn) {
    int col = n0 + wn * 64 + fn * 16 + l15;
    float bvv = bias[col];
#pragma unroll
    for (int fm = 0; fm < 2; ++fm) {
      int rowb = m0 + wm * 32 + fm * 16 + l4 * 4;
#pragma unroll
      for (int r = 0; r < 4; ++r)
        C[(rowb + r) * 512 + col] = acc[fm][fn][r] + bvv;
    }
  }
}

// ---------------- V transpose: vp[n][t][h*64+d] -> vt[nh*64+d][t_perm] ----------------
// Output t-order is permuted within each 32-t block so the attn PV B-fragment
// {t = B*32 + g*4+(j&3) + 16*(j>>2), j=0..7} is one contiguous 8-elem group:
// position p = g*8+j  stores  t = (p&32) + ((p>>3)&3)*4 + (p&3) + ((p>>2)&1)*16.
__global__ __launch_bounds__(256) void transpose_v(const u16* __restrict__ vp,
                                                   u16* __restrict__ vt) {
  __shared__ u16 L[64 * 72];  // 64x64 tile, stride 72 breaks bank alignment
  const int bid = blockIdx.x;  // 1024 = 32 t-tiles x 32 nh
  const int nh = bid & 31, tt = bid >> 5;
  const int n = nh >> 3, h = nh & 7;
  const u16* src = vp + (n * 2048 + tt * 64) * 512 + h * 64;
  const int tid = threadIdx.x;
#pragma unroll
  for (int i = 0; i < 2; ++i) {
    int c = tid + 256 * i;
    int row = c >> 3, dg = c & 7;
    uint4 x = *(const uint4*)(src + row * 512 + dg * 8);
    *(uint4*)&L[row * 72 + dg * 8] = x;
  }
  __syncthreads();
  u16* dst = vt + nh * 64 * 2048 + tt * 64;
#pragma unroll
  for (int i = 0; i < 2; ++i) {
    int c = tid + 256 * i;
    int d = c >> 3, tg = c & 7;
    u16 e[8];
#pragma unroll
    for (int j = 0; j < 8; ++j) {
      int tsrc = (tg & 4) * 8 + (tg & 3) * 4 + (j & 3) + (j >> 2) * 16;
      e[j] = L[tsrc * 72 + d];
    }
    uint4 o;
    o.x = (u32)e[0] | ((u32)e[1] << 16);
    o.y = (u32)e[2] | ((u32)e[3] << 16);
    o.z = (u32)e[4] | ((u32)e[5] << 16);
    o.w = (u32)e[6] | ((u32)e[7] << 16);
    *(uint4*)(dst + d * 2048 + tg * 8) = o;
  }
}

// ---------------- Flash attention, causal, S^T formulation, staggered pipeline ----
// grid 1024 = 32 q-tiles (64 rows) x 32 nh; heavy q-tiles first.
// Steady state per step (no vmcnt(0) drain):
//   [K(it) in LDS, V(it) in flight]
//   vmcnt(4)+bar  -> QK^T reads Ks -> lgkm(0)+bar -> issue K(it+1)
//   softmax       -> vmcnt(4)+bar  -> PV reads Vts -> lgkm(0)+bar -> issue V(it+1)
// K-load latency hides under softmax+PV; V-load latency hides under QK^T+softmax.
__global__ __launch_bounds__(256) void attn_kernel(const u16* __restrict__ Qg,
                                                   const u16* __restrict__ Kg,
                                                   const u16* __restrict__ Vt,
                                                   u16* __restrict__ Yg) {
  __shared__ u16 Qs[64 * 64];    // Q tile [m][d], source-swizzled chunks   (8 KB)
  __shared__ u16 Ks[128 * 64];   // K tile [t][d], source-swizzled chunks   (16 KB)
  __shared__ u16 Vts[64 * 128];  // V^T tile [d][t_perm], swizzled chunks   (16 KB)
  // total 40960 B -> 4 blocks/CU

  const int bid = blockIdx.x;
  const int nh = bid & 31;
  const int qt = 31 - (bid >> 5);  // heavy (long) q-tiles first
  const int n = nh >> 3, h = nh & 7;
  const int tid = threadIdx.x, lane = tid & 63, w = tid >> 6;
  const int l15 = lane & 15, l4 = lane >> 4;
  const int s0 = qt * 64;

  const u16* Qb = Qg + (n * 2048 + s0) * 512 + h * 64;
  const u16* Kb = Kg + n * 2048 * 512 + h * 64;
  const u16* Vb = Vt + nh * 64 * 2048;

  // ---- prologue: issue Q (2), K(0) (4), V(0) (4) ----
#pragma unroll
  for (int i = 0; i < 2; ++i) {
    int c = tid + 256 * i;
    int row = c >> 3, dg = (c & 7) ^ (row & 7);
    cp16(&Qs[c * 8], Qb + row * 512 + dg * 8);
  }
#pragma unroll
  for (int i = 0; i < 4; ++i) {
    int c = tid + 256 * i;
    int t = c >> 3, dg = (c & 7) ^ (t & 7);
    cp16(&Ks[c * 8], Kb + t * 512 + dg * 8);
  }
#pragma unroll
  for (int i = 0; i < 4; ++i) {
    int c = tid + 256 * i;
    int d = c >> 4, x = c & 15;
    cp16(&Vts[c * 8], Vb + d * 2048 + ((x ^ (d & 15)) * 8));
  }
  WAIT_VM(8);  // Q landed (K0,V0 still in flight)
  BARRIER;
  const int qr = w * 16 + l15;
  bf16x8 qf0 = *(const bf16x8*)&Qs[qr * 64 + ((l4 ^ (qr & 7)) * 8)];
  bf16x8 qf1 = *(const bf16x8*)&Qs[qr * 64 + (((4 + l4) ^ (qr & 7)) * 8)];

  f32x4 accO[4] = {};
  float mrow = -1e30f, lrow = 0.f;  // softmax state for column m = l15
  const int sgl = s0 + w * 16 + l15;

  const int ntiles = (qt >> 1) + 1;
  for (int it = 0; it < ntiles; ++it) {
    const int t0 = it * 128;
    const bool more = (it + 1 < ntiles);

    WAIT_VM(4);  // K(it) landed; V(it) (newest 4) still in flight
    BARRIER;

    // ---- S^T = K Q^T : 8 frags along t (rows), cols m = l15. Q pre-scaled. ----
    f32x4 st[8];
    __builtin_amdgcn_s_setprio(1);
#pragma unroll
    for (int fn = 0; fn < 8; ++fn) {
      int tr = fn * 16 + l15;
      bf16x8 k0 = *(const bf16x8*)&Ks[tr * 64 + ((l4 ^ (tr & 7)) * 8)];
      bf16x8 k1 = *(const bf16x8*)&Ks[tr * 64 + (((4 + l4) ^ (tr & 7)) * 8)];
      f32x4 a = {};
      a = MFMA_BF16(k0, qf0, a);
      st[fn] = MFMA_BF16(k1, qf1, a);
    }
    __builtin_amdgcn_s_setprio(0);

    WAIT_LG;   // my Ks reads fully complete (bank access done)
    BARRIER;   // all waves done reading Ks -> safe to overwrite
    if (more) {
#pragma unroll
      for (int i = 0; i < 4; ++i) {  // issue K(it+1); latency hides under softmax+PV
        int c = tid + 256 * i;
        int t = c >> 3, dg = (c & 7) ^ (t & 7);
        cp16(&Ks[c * 8], Kb + (t0 + 128 + t) * 512 + dg * 8);
      }
    }

    // ---- online softmax, exp2 domain; this lane owns column m = l15 ----
    const bool diag = (t0 + 128 > s0);  // true only on the last tile
    float rmax = -1e30f;
#pragma unroll
    for (int fn = 0; fn < 8; ++fn)
#pragma unroll
      for (int r = 0; r < 4; ++r) {
        float v = st[fn][r];
        if (diag) {
          int tg = t0 + fn * 16 + l4 * 4 + r;
          if (tg > sgl) v = -1e30f;
        }
        st[fn][r] = v;
        rmax = fmaxf(rmax, v);
      }
    rmax = fmaxf(rmax, __shfl_xor(rmax, 16));
    rmax = fmaxf(rmax, __shfl_xor(rmax, 32));
    // defer-rescale: only pay alpha shuffle + O rescale when max grew by >10 exp2 units.
    if (__any(rmax > mrow + 10.f)) {
      float mnew = fmaxf(mrow, rmax);
      float alpha = __builtin_amdgcn_exp2f(mrow - mnew);
      mrow = mnew;
      lrow *= alpha;
      float aO[4];
#pragma unroll
      for (int r = 0; r < 4; ++r) aO[r] = __shfl(alpha, (lane & 48) | (l4 * 4 + r));
#pragma unroll
      for (int fd = 0; fd < 4; ++fd)
#pragma unroll
        for (int r = 0; r < 4; ++r) accO[fd][r] *= aO[r];
    }
    float rsum = 0.f;
#pragma unroll
    for (int fn = 0; fn < 8; ++fn)
#pragma unroll
      for (int r = 0; r < 4; ++r) {
        float p = __builtin_amdgcn_exp2f(st[fn][r] - mrow);
        st[fn][r] = p;
        rsum += p;
      }
    rsum += __shfl_xor(rsum, 16);
    rsum += __shfl_xor(rsum, 32);
    lrow += rsum;

    // ---- P -> bf16 A-frags in registers; pa[ks] slot j = P[m][ks*32+16*(j>>2)+l4*4+(j&3)]
    bf16x8 pa[4];
#pragma unroll
    for (int ks = 0; ks < 4; ++ks) {
      bf16x8 t;
      t[0] = (__bf16)st[2 * ks][0];     t[1] = (__bf16)st[2 * ks][1];
      t[2] = (__bf16)st[2 * ks][2];     t[3] = (__bf16)st[2 * ks][3];
      t[4] = (__bf16)st[2 * ks + 1][0]; t[5] = (__bf16)st[2 * ks + 1][1];
      t[6] = (__bf16)st[2 * ks + 1][2]; t[7] = (__bf16)st[2 * ks + 1][3];
      pa[ks] = t;
    }

    if (more) { WAIT_VM(4); }  // V(it) landed; K(it+1) (newest 4) in flight
    else      { WAIT_VM(0); }
    BARRIER;

    // ---- O += P V : B-frag = one b128; permuted vt layout matches pa's k-relabel ----
    __builtin_amdgcn_s_setprio(1);
#pragma unroll
    for (int ks = 0; ks < 4; ++ks) {
#pragma unroll
      for (int fd = 0; fd < 4; ++fd) {
        int d = fd * 16 + l15;
        bf16x8 bv = *(const bf16x8*)&Vts[d * 128 + (((ks * 4 + l4) ^ l15) * 8)];
        accO[fd] = MFMA_BF16(pa[ks], bv, accO[fd]);
      }
    }
    __builtin_amdgcn_s_setprio(0);

    WAIT_LG;   // my Vts reads fully complete
    BARRIER;   // all waves done reading Vts -> safe to overwrite
    if (more) {
#pragma unroll
      for (int i = 0; i < 4; ++i) {  // issue V(it+1); latency hides under next QK^T
        int c = tid + 256 * i;
        int d = c >> 4, x = c & 15;
        cp16(&Vts[c * 8], Vb + d * 2048 + (t0 + 128) + ((x ^ (d & 15)) * 8));
      }
    }
  }

  // ---- epilogue ----
  float lO[4];
#pragma unroll
  for (int r = 0; r < 4; ++r) lO[r] = __shfl(lrow, (lane & 48) | (l4 * 4 + r));
#pragma unroll
  for (int fd = 0; fd < 4; ++fd)
#pragma unroll
    for (int r = 0; r < 4; ++r) {
      int row = s0 + w * 16 + l4 * 4 + r;
      int col = h * 64 + fd * 16 + l15;
      Yg[(n * 2048 + row) * 512 + col] = f2bf(accO[fd][r] / lO[r]);
    }
}

extern "C" void kernel_launch(void* const* d_in, const int* in_sizes, int n_in,
                              void* d_out, int out_size, void* d_ws, size_t ws_size,
                              hipStream_t stream) {
  (void)in_sizes; (void)n_in; (void)out_size; (void)ws_size;
  const float* query = (const float*)d_in[0];
  const float* key_  = (const float*)d_in[1];
  const float* value = (const float*)d_in[2];
  // d_in[3] = attn_mask (tril) — causal, applied structurally
  const float* Wq = (const float*)d_in[4];
  const float* bq = (const float*)d_in[5];
  const float* Wk = (const float*)d_in[6];
  const float* bk = (const float*)d_in[7];
  const float* Wv = (const float*)d_in[8];
  const float* bv = (const float*)d_in[9];
  const float* Wp = (const float*)d_in[10];
  const float* bp = (const float*)d_in[11];

  char* ws = (char*)d_ws;  // 50 MB total
  u16* qx  = (u16*)(ws);                // 8 MB; reused as y after q-proj
  u16* kx  = (u16*)(ws + 8388608);      // 8 MB; reused as vt after k-proj
  u16* vx  = (u16*)(ws + 16777216);     // 8 MB
  u16* wqx = (u16*)(ws + 25165824);
  u16* wkx = (u16*)(ws + 25690112);
  u16* wvx = (u16*)(ws + 26214400);
  u16* wpx = (u16*)(ws + 26738688);
  u16* qp  = (u16*)(ws + 27262976);     // 8 MB
  u16* kp  = (u16*)(ws + 35651584);     // 8 MB
  u16* vp  = (u16*)(ws + 44040192);     // 8 MB
  u16* y   = qx;
  u16* vt  = kx;  // kx dead after gemm_qkv

  cast_all<<<13312, 256, 0, stream>>>(query, key_, value, Wq, Wk, Wv, Wp,
                                      qx, kx, vx, wqx, wkx, wvx, wpx);
  gemm_qkv<<<dim3(12, 64), 256, 0, stream>>>(qx, kx, vx, wqx, wkx, wvx,
                                             bq, bk, bv, qp, kp, vp);
  transpose_v<<<1024, 256, 0, stream>>>(vp, vt);
  attn_kernel<<<1024, 256, 0, stream>>>(qp, kp, vt, y);
  gemm_out<<<dim3(4, 128), 256, 0, stream>>>(y, wpx, bp, (float*)d_out);
}